// Round 19
// baseline (272.298 us; speedup 1.0000x reference)
//
#include <hip/hip_runtime.h>

typedef _Float16 hp2 __attribute__((ext_vector_type(2)));

#define NB    1024
#define TT    256
#define EE    100
#define VOCAB 5000
#define GG1   256   // 4*H1
#define GG2   128   // 4*H2

__device__ __forceinline__ float fast_sigmoid(float x) {
  return __builtin_amdgcn_rcpf(1.0f + __expf(-x));
}
__device__ __forceinline__ float fast_tanh(float x) {
  return 1.0f - 2.0f * __builtin_amdgcn_rcpf(1.0f + __expf(2.0f * x));
}

// Counted-wait barrier: drain LDS ops only; global zx prefetch stays in flight.
__device__ __forceinline__ void step_sync() {
  asm volatile("s_waitcnt lgkmcnt(0)" ::: "memory");
  __builtin_amdgcn_s_barrier();
  __builtin_amdgcn_sched_barrier(0);
}

// ---- K1: emb_zi[v][u*4+g] = b1[g*64+u] + sum_k emb[v][k]*W1[k][g*64+u] ----
__global__ __launch_bounds__(256) void emb_gemm(
    const float* __restrict__ emb, const float* __restrict__ W1,
    const float* __restrict__ b1, float* __restrict__ emb_zi)
{
  __shared__ float sE[8][EE];
  const int j  = threadIdx.x;           // column g*64+u
  const int v0 = blockIdx.x * 8;
  for (int idx = j; idx < 8 * EE; idx += 256) {
    int r = idx / EE, k = idx % EE;
    sE[r][k] = emb[(size_t)(v0 + r) * EE + k];
  }
  __syncthreads();
  float acc[8];
  const float bb = b1[j];
  #pragma unroll
  for (int r = 0; r < 8; ++r) acc[r] = bb;
  for (int k = 0; k < EE; ++k) {
    float w = W1[k * GG1 + j];
    #pragma unroll
    for (int r = 0; r < 8; ++r) acc[r] = fmaf(sE[r][k], w, acc[r]);
  }
  const int slot = (j & 63) * 4 + (j >> 6);   // u*4 + g
  #pragma unroll
  for (int r = 0; r < 8; ++r) emb_zi[(size_t)(v0 + r) * GG1 + slot] = acc[r];
}

// ---- K2: one block = one row, FOUR waves, unit-split, 1 barrier/step ----
// w0: L1 units [0,32)  — lane (ul=l&31, s=l>>5): unit ul, k-half s; xor(32) reduce
// w1: L1 units [32,64) — same with ubase=32
// w2: L2 units [0,16)  — lane (u2=l&15, ss=l>>4): k-quarter ss; xor(16)+xor(32)
// w3: L2 units [16,32) — same with u2base=16
// All reductions in-wave; parity dataflow identical to round 16 (read t&1,
// write (t&1)^1); one counted-wait barrier per step. 1024 blocks x 4 waves
// = 4 waves/SIMD; waves_per_eu(4,4) -> 128-reg budget (64/48 weight hp2s fit).
__global__ __launch_bounds__(256) __attribute__((amdgpu_waves_per_eu(4, 4)))
void lstm_quad(
    const int* __restrict__ tokens, const float* __restrict__ emb_zi,
    const float* __restrict__ U1,
    const float* __restrict__ W2, const float* __restrict__ U2, const float* __restrict__ b2,
    const float* __restrict__ Wd, const float* __restrict__ bd,
    float* __restrict__ out)
{
  __shared__ __align__(16) _Float16 sHB[2][96];  // 0..63 h1, 64..95 h2
  __shared__ int sTok[TT];

  const int tid = threadIdx.x;
  const int l   = tid & 63;
  const int wv  = tid >> 6;           // wave role 0..3
  const int row = blockIdx.x;

  // ---- stage tokens + zero h buffers ----
  if (tid < 128) ((int2*)sTok)[tid] = ((const int2*)(tokens + (size_t)row * TT))[tid];
  if (tid < 96) { sHB[0][tid] = (_Float16)0.0f; sHB[1][tid] = (_Float16)0.0f; }

  if (wv < 2) {
    // ================= L1 wave: units [32*wv, 32*wv+32) =================
    const int ul = l & 31;
    const int s  = l >> 5;            // k-half: k in [32s, 32s+32)
    const int u  = 32 * wv + ul;
    hp2 wA[64];   // wA[4p+g] = {U1[k0][g*64+u], U1[k0+1][g*64+u]}, k0 = 32s+2p
    #pragma unroll
    for (int p = 0; p < 16; ++p) {
      int k0 = 32 * s + 2 * p;
      #pragma unroll
      for (int g = 0; g < 4; ++g) {
        hp2 w;
        w[0] = (_Float16)U1[(k0 + 0) * GG1 + g * 64 + u];
        w[1] = (_Float16)U1[(k0 + 1) * GG1 + g * 64 + u];
        wA[4 * p + g] = w;
      }
    }
    __syncthreads();                  // tokens + zeroed buffers visible

    float c1 = 0.f, h1r = 0.f;
    // ---- prologue: h1(0) from zx(0); all lanes compute (s-pair redundant) ----
    {
      int tok0 = sTok[0];
      float4 zx0 = *(const float4*)&emb_zi[(size_t)tok0 * GG1 + 4 * u];
      if (tok0 != 0) {
        float iv = fast_sigmoid(zx0.x);
        float gv = fast_tanh(zx0.z);
        float ov = fast_sigmoid(zx0.w);
        c1 = iv * gv; h1r = ov * fast_tanh(c1);
      }
      if (s == 0) sHB[0][u] = (_Float16)h1r;
    }
    int   tok_a = sTok[1];            // token(t+1) for the A-step
    float4 zxa = *(const float4*)&emb_zi[(size_t)tok_a * GG1 + 4 * u];
    step_sync();

    for (int t = 0; t < TT; ++t) {
      if (t + 1 < TT) {               // ---- compute h1(t+1) from h1(t) ----
        // prefetch zx(t+2): rides across the barrier (lgkm-only sync)
        int tok_n = 0;
        float4 zxn = zxa;
        if (t + 2 < TT) {
          tok_n = sTok[t + 2];
          zxn = *(const float4*)&emb_zi[(size_t)tok_n * GG1 + 4 * u];
        }
        float a0 = 0.f, a1 = 0.f, a2 = 0.f, a3 = 0.f;
        const int4* rb = (const int4*)&sHB[t & 1][32 * s];  // this lane's k-half
        #pragma unroll
        for (int q = 0; q < 4; ++q) {           // 4 x b128 = 32 halves = 16 pairs
          int4 hq = rb[q];
          #pragma unroll
          for (int pp = 0; pp < 4; ++pp) {
            const int p = 4 * q + pp;
            hp2 hv = ((const hp2*)&hq)[pp];
            a0 = __builtin_amdgcn_fdot2(hv, wA[4 * p + 0], a0, false);
            a1 = __builtin_amdgcn_fdot2(hv, wA[4 * p + 1], a1, false);
            a2 = __builtin_amdgcn_fdot2(hv, wA[4 * p + 2], a2, false);
            a3 = __builtin_amdgcn_fdot2(hv, wA[4 * p + 3], a3, false);
          }
        }
        a0 += __shfl_xor(a0, 32);     // combine k-halves (in-wave)
        a1 += __shfl_xor(a1, 32);
        a2 += __shfl_xor(a2, 32);
        a3 += __shfl_xor(a3, 32);
        {
          const bool ma = (tok_a != 0);
          float iv = fast_sigmoid(a0 + zxa.x);
          float fv = fast_sigmoid(a1 + zxa.y);
          float gv = fast_tanh(a2 + zxa.z);
          float ov = fast_sigmoid(a3 + zxa.w);
          if (ma) { c1 = fv * c1 + iv * gv; h1r = ov * fast_tanh(c1); }
        }
        if (s == 0) sHB[(t & 1) ^ 1][u] = (_Float16)h1r;
        tok_a = tok_n; zxa = zxn;
      }
      step_sync();
    }
  } else {
    // ================= L2 wave: units [16*(wv-2), 16*(wv-2)+16) =================
    const int u2 = 16 * (wv - 2) + (l & 15);
    const int ss = l >> 4;            // k-quarter: k in [24ss, 24ss+24)
    hp2 wB[48];   // wB[4p+g] = combined [W2;U2] k-pair, k0 = 24ss+2p, col g*32+u2
    #pragma unroll
    for (int p = 0; p < 12; ++p) {
      int k0 = 24 * ss + 2 * p;       // even: never straddles the 64 boundary
      const float* r0 = (k0     < 64) ? &W2[(size_t)k0 * GG2]       : &U2[(size_t)(k0 - 64) * GG2];
      const float* r1 = (k0 + 1 < 64) ? &W2[(size_t)(k0 + 1) * GG2] : &U2[(size_t)(k0 + 1 - 64) * GG2];
      #pragma unroll
      for (int g = 0; g < 4; ++g) {
        hp2 w;
        w[0] = (_Float16)r0[g * 32 + u2];
        w[1] = (_Float16)r1[g * 32 + u2];
        wB[4 * p + g] = w;
      }
    }
    const float bi2 = b2[u2], bf2 = b2[32 + u2], bg2 = b2[64 + u2], bo2 = b2[96 + u2];
    __syncthreads();                  // tokens + zeroed buffers visible

    float c2 = 0.f, h2r = 0.f;
    step_sync();                      // pairs with L1 prologue sync

    for (int t = 0; t < TT; ++t) {
      // ---- h2(t) from [h1(t) | h2(t-1)] at parity t&1 ----
      const int tok_b = sTok[t];
      float b0 = 0.f, b1v = 0.f, b2v = 0.f, b3 = 0.f;
      const int4* hbp = (const int4*)(&sHB[t & 1][24 * ss]);  // 4 addrs/wave
      #pragma unroll
      for (int q = 0; q < 3; ++q) {             // 3 x b128 = 24 halves = 12 pairs
        int4 hq = hbp[q];
        #pragma unroll
        for (int pp = 0; pp < 4; ++pp) {
          const int p = 4 * q + pp;
          hp2 hv = ((const hp2*)&hq)[pp];
          b0  = __builtin_amdgcn_fdot2(hv, wB[4 * p + 0], b0,  false);
          b1v = __builtin_amdgcn_fdot2(hv, wB[4 * p + 1], b1v, false);
          b2v = __builtin_amdgcn_fdot2(hv, wB[4 * p + 2], b2v, false);
          b3  = __builtin_amdgcn_fdot2(hv, wB[4 * p + 3], b3,  false);
        }
      }
      b0  += __shfl_xor(b0, 16);  b0  += __shfl_xor(b0, 32);
      b1v += __shfl_xor(b1v, 16); b1v += __shfl_xor(b1v, 32);
      b2v += __shfl_xor(b2v, 16); b2v += __shfl_xor(b2v, 32);
      b3  += __shfl_xor(b3, 16);  b3  += __shfl_xor(b3, 32);
      {
        const bool mb = (tok_b != 0);
        float i2 = fast_sigmoid(b0 + bi2);
        float f2 = fast_sigmoid(b1v + bf2);
        float g2 = fast_tanh(b2v + bg2);
        float o2 = fast_sigmoid(b3 + bo2);
        if (mb) { c2 = f2 * c2 + i2 * g2; h2r = o2 * fast_tanh(c2); }
      }
      if (ss == 0) sHB[(t & 1) ^ 1][64 + u2] = (_Float16)h2r;
      step_sync();
    }
  }
  __syncthreads();

  // ---- epilogue: h2(TT-1) in parity ((TT-1)&1)^1 = 0 ----
  if (tid < 4) {
    float a = bd[tid];
    #pragma unroll
    for (int k = 0; k < 32; ++k)
      a = fmaf((float)sHB[0][64 + k], Wd[k * 4 + tid], a);
    out[(size_t)row * 4 + tid] = fast_sigmoid(a);
  }
}

extern "C" void kernel_launch(void* const* d_in, const int* in_sizes, int n_in,
                              void* d_out, int out_size, void* d_ws, size_t ws_size,
                              hipStream_t stream) {
  const int*   tokens = (const int*)d_in[0];
  const float* emb    = (const float*)d_in[1];
  const float* W1     = (const float*)d_in[2];
  const float* U1     = (const float*)d_in[3];
  const float* b1     = (const float*)d_in[4];
  const float* W2     = (const float*)d_in[5];
  const float* U2     = (const float*)d_in[6];
  const float* b2     = (const float*)d_in[7];
  const float* Wd     = (const float*)d_in[8];
  const float* bd     = (const float*)d_in[9];
  float* out    = (float*)d_out;
  float* emb_zi = (float*)d_ws;         // 5000*256*4 = 5.12 MB scratch

  emb_gemm<<<dim3(VOCAB / 8), dim3(256), 0, stream>>>(emb, W1, b1, emb_zi);
  lstm_quad<<<dim3(NB), dim3(256), 0, stream>>>(
      tokens, emb_zi, U1, W2, U2, b2, Wd, bd, out);
}

// Round 20
// 230.538 us; speedup vs baseline: 1.1811x; 1.1811x over previous
//
#include <hip/hip_runtime.h>

typedef _Float16 hp2 __attribute__((ext_vector_type(2)));

#define NB    1024
#define TT    256
#define EE    100
#define VOCAB 5000
#define GG1   256   // 4*H1
#define GG2   128   // 4*H2
#define CHK   8     // steps per chunk
#define NCH   (TT / CHK)

__device__ __forceinline__ float fast_sigmoid(float x) {
  return __builtin_amdgcn_rcpf(1.0f + __expf(-x));
}
__device__ __forceinline__ float fast_tanh(float x) {
  return 1.0f - 2.0f * __builtin_amdgcn_rcpf(1.0f + __expf(2.0f * x));
}

// Chunk barrier: drain LDS only; global zx prefetch stays in flight.
__device__ __forceinline__ void chunk_sync() {
  asm volatile("s_waitcnt lgkmcnt(0)" ::: "memory");
  __builtin_amdgcn_s_barrier();
  __builtin_amdgcn_sched_barrier(0);
}
// In-wave LDS ordering fence (LDS ops of one wave execute in order; this
// just stops the compiler from reordering across it).
__device__ __forceinline__ void lds_fence() {
  asm volatile("" ::: "memory");
}

// ---- K1: emb_zi[v][u*4+g] = b1[g*64+u] + sum_k emb[v][k]*W1[k][g*64+u] ----
__global__ __launch_bounds__(256) void emb_gemm(
    const float* __restrict__ emb, const float* __restrict__ W1,
    const float* __restrict__ b1, float* __restrict__ emb_zi)
{
  __shared__ float sE[8][EE];
  const int j  = threadIdx.x;           // column g*64+u
  const int v0 = blockIdx.x * 8;
  for (int idx = j; idx < 8 * EE; idx += 256) {
    int r = idx / EE, k = idx % EE;
    sE[r][k] = emb[(size_t)(v0 + r) * EE + k];
  }
  __syncthreads();
  float acc[8];
  const float bb = b1[j];
  #pragma unroll
  for (int r = 0; r < 8; ++r) acc[r] = bb;
  for (int k = 0; k < EE; ++k) {
    float w = W1[k * GG1 + j];
    #pragma unroll
    for (int r = 0; r < 8; ++r) acc[r] = fmaf(sE[r][k], w, acc[r]);
  }
  const int slot = (j & 63) * 4 + (j >> 6);   // u*4 + g
  #pragma unroll
  for (int r = 0; r < 8; ++r) emb_zi[(size_t)(v0 + r) * GG1 + slot] = acc[r];
}

// ---- K2: one block = one row; wave0 = L1 free-running (no barriers),
//          wave1 = L2 one chunk behind; 33 barriers total ----
// hist1[t][64]: full h1 history (L1 never reads h2 -> one-directional dep).
// In-wave h1(t-1) visibility: LDS ops of a wave execute in order.
// h2buf[32]: L2's own state, wave-internal (read-then-write per step).
__global__ __launch_bounds__(128) __attribute__((amdgpu_waves_per_eu(2, 2)))
void lstm_pipe(
    const int* __restrict__ tokens, const float* __restrict__ emb_zi,
    const float* __restrict__ U1,
    const float* __restrict__ W2, const float* __restrict__ U2, const float* __restrict__ b2,
    const float* __restrict__ Wd, const float* __restrict__ bd,
    float* __restrict__ out)
{
  __shared__ __align__(16) _Float16 hist1[TT][64];   // 32 KB
  __shared__ __align__(16) _Float16 h2buf[32];
  __shared__ int sTok[TT];

  const int tid = threadIdx.x;
  const int u   = tid & 63;
  const int wv  = tid >> 6;           // 0: L1 wave, 1: L2 wave
  const int row = blockIdx.x;

  ((int2*)sTok)[tid] = ((const int2*)(tokens + (size_t)row * TT))[tid];
  if (tid < 32) h2buf[tid] = (_Float16)0.0f;

  if (wv == 0) {
    // ================= L1 wave: lane u owns unit u (r16 body) ================
    hp2 wA[128];   // wA[4p+g] = {U1[2p][g*64+u], U1[2p+1][g*64+u]}, p=0..31
    #pragma unroll
    for (int p = 0; p < 32; ++p) {
      #pragma unroll
      for (int g = 0; g < 4; ++g) {
        hp2 w;
        w[0] = (_Float16)U1[(2 * p + 0) * GG1 + g * 64 + u];
        w[1] = (_Float16)U1[(2 * p + 1) * GG1 + g * 64 + u];
        wA[4 * p + g] = w;
      }
    }
    #define PIN16(B) asm volatile("" : "+v"(wA[B+0]),"+v"(wA[B+1]),"+v"(wA[B+2]),"+v"(wA[B+3]),\
      "+v"(wA[B+4]),"+v"(wA[B+5]),"+v"(wA[B+6]),"+v"(wA[B+7]),"+v"(wA[B+8]),"+v"(wA[B+9]),\
      "+v"(wA[B+10]),"+v"(wA[B+11]),"+v"(wA[B+12]),"+v"(wA[B+13]),"+v"(wA[B+14]),"+v"(wA[B+15]))
    PIN16(0); PIN16(16); PIN16(32); PIN16(48);
    PIN16(64); PIN16(80); PIN16(96); PIN16(112);
    #undef PIN16
    __syncthreads();                  // tokens + h2buf visible everywhere

    float c1 = 0.f, h1r = 0.f;
    // ---- t = 0: h1(0) from zx(0) only ----
    {
      int tok0 = sTok[0];
      float4 zx0 = *(const float4*)&emb_zi[(size_t)tok0 * GG1 + 4 * u];
      if (tok0 != 0) {
        float iv = fast_sigmoid(zx0.x);
        float gv = fast_tanh(zx0.z);
        float ov = fast_sigmoid(zx0.w);
        c1 = iv * gv; h1r = ov * fast_tanh(c1);
      }
      hist1[0][u] = (_Float16)h1r;
      lds_fence();
    }
    // zx slots: odd t -> A, even t -> B
    int   tokA = sTok[1];
    float4 zxA = *(const float4*)&emb_zi[(size_t)tokA * GG1 + 4 * u];
    int   tokB = sTok[2];
    float4 zxB = *(const float4*)&emb_zi[(size_t)tokB * GG1 + 4 * u];

    for (int c = 0; c <= NCH; ++c) {
      if (c < NCH) {
        #pragma unroll
        for (int tt = 0; tt < CHK; ++tt) {
          const int t = CHK * c + tt;
          if (t == 0) continue;       // done in prologue (only c==0,tt==0)
          // consume slot by parity; reissue for t+2 (rides across barriers)
          float4 zc; int tokc;
          if (t & 1) { zc = zxA; tokc = tokA; }
          else       { zc = zxB; tokc = tokB; }
          if (t + 2 < TT) {
            int tok_n = sTok[t + 2];
            float4 zn = *(const float4*)&emb_zi[(size_t)tok_n * GG1 + 4 * u];
            if (t & 1) { zxA = zn; tokA = tok_n; }
            else       { zxB = zn; tokB = tok_n; }
          }
          float a0 = 0.f, a1 = 0.f, a2 = 0.f, a3 = 0.f;
          const int4* rb = (const int4*)&hist1[t - 1][0];   // uniform reads
          #pragma unroll
          for (int q = 0; q < 8; ++q) {
            int4 hq = rb[q];
            #pragma unroll
            for (int pp = 0; pp < 4; ++pp) {
              const int p = 4 * q + pp;
              hp2 hv = ((const hp2*)&hq)[pp];
              a0 = __builtin_amdgcn_fdot2(hv, wA[4 * p + 0], a0, false);
              a1 = __builtin_amdgcn_fdot2(hv, wA[4 * p + 1], a1, false);
              a2 = __builtin_amdgcn_fdot2(hv, wA[4 * p + 2], a2, false);
              a3 = __builtin_amdgcn_fdot2(hv, wA[4 * p + 3], a3, false);
            }
          }
          {
            const bool ma = (tokc != 0);
            float iv = fast_sigmoid(a0 + zc.x);
            float fv = fast_sigmoid(a1 + zc.y);
            float gv = fast_tanh(a2 + zc.z);
            float ov = fast_sigmoid(a3 + zc.w);
            if (ma) { c1 = fv * c1 + iv * gv; h1r = ov * fast_tanh(c1); }
          }
          hist1[t][u] = (_Float16)h1r;
          lds_fence();                // in-wave order: write(t) before read(t)
        }
      }
      chunk_sync();                   // publish chunk c to the L2 wave
    }
  } else {
    // ================= L2 wave: unit u2 = u&31, k-half s = u>>5 ===============
    const int u2 = u & 31;
    const int s  = u >> 5;
    hp2 wB[96];    // wB[4p+g] = combined [W2;U2] k-pair, k0 = 48s+2p
    #pragma unroll
    for (int p = 0; p < 24; ++p) {
      int k0 = 48 * s + 2 * p;        // even: never straddles the 64 boundary
      const float* r0 = (k0     < 64) ? &W2[(size_t)k0 * GG2]       : &U2[(size_t)(k0 - 64) * GG2];
      const float* r1 = (k0 + 1 < 64) ? &W2[(size_t)(k0 + 1) * GG2] : &U2[(size_t)(k0 + 1 - 64) * GG2];
      #pragma unroll
      for (int g = 0; g < 4; ++g) {
        hp2 w;
        w[0] = (_Float16)r0[g * 32 + u2];
        w[1] = (_Float16)r1[g * 32 + u2];
        wB[4 * p + g] = w;
      }
    }
    #define PIN16B(B) asm volatile("" : "+v"(wB[B+0]),"+v"(wB[B+1]),"+v"(wB[B+2]),"+v"(wB[B+3]),\
      "+v"(wB[B+4]),"+v"(wB[B+5]),"+v"(wB[B+6]),"+v"(wB[B+7]),"+v"(wB[B+8]),"+v"(wB[B+9]),\
      "+v"(wB[B+10]),"+v"(wB[B+11]),"+v"(wB[B+12]),"+v"(wB[B+13]),"+v"(wB[B+14]),"+v"(wB[B+15]))
    PIN16B(0); PIN16B(16); PIN16B(32); PIN16B(48); PIN16B(64); PIN16B(80);
    #undef PIN16B
    const float bi2 = b2[u2], bf2 = b2[32 + u2], bg2 = b2[64 + u2], bo2 = b2[96 + u2];
    __syncthreads();

    float c2 = 0.f, h2r = 0.f;
    for (int c = 0; c <= NCH; ++c) {
      if (c >= 1) {
        const int cc = c - 1;         // consume chunk cc (published at barrier cc)
        #pragma unroll
        for (int tt = 0; tt < CHK; ++tt) {
          const int t = CHK * cc + tt;
          const int tok_b = sTok[t];
          float b0 = 0.f, b1v = 0.f, b2v = 0.f, b3 = 0.f;
          #pragma unroll
          for (int q = 0; q < 6; ++q) {
            const int k0 = 48 * s + 8 * q;      // half-index in [h1(t) | h2(t-1)]
            const _Float16* src = (k0 < 64) ? &hist1[t][k0] : &h2buf[k0 - 64];
            int4 hq = *(const int4*)src;
            #pragma unroll
            for (int pp = 0; pp < 4; ++pp) {
              const int p = 4 * q + pp;
              hp2 hv = ((const hp2*)&hq)[pp];
              b0  = __builtin_amdgcn_fdot2(hv, wB[4 * p + 0], b0,  false);
              b1v = __builtin_amdgcn_fdot2(hv, wB[4 * p + 1], b1v, false);
              b2v = __builtin_amdgcn_fdot2(hv, wB[4 * p + 2], b2v, false);
              b3  = __builtin_amdgcn_fdot2(hv, wB[4 * p + 3], b3,  false);
            }
          }
          b0  += __shfl_xor(b0, 32);
          b1v += __shfl_xor(b1v, 32);
          b2v += __shfl_xor(b2v, 32);
          b3  += __shfl_xor(b3, 32);
          {
            const bool mb = (tok_b != 0);
            float i2 = fast_sigmoid(b0 + bi2);
            float f2 = fast_sigmoid(b1v + bf2);
            float g2 = fast_tanh(b2v + bg2);
            float o2 = fast_sigmoid(b3 + bo2);
            if (mb) { c2 = f2 * c2 + i2 * g2; h2r = o2 * fast_tanh(c2); }
          }
          if (s == 0) h2buf[u2] = (_Float16)h2r;  // read-before-write in-order
          lds_fence();
        }
      }
      chunk_sync();
    }
  }
  __syncthreads();

  // ---- epilogue: out = sigmoid(h2(255) @ Wd + bd); h2(255) is in h2buf ----
  if (tid < 4) {
    float a = bd[tid];
    #pragma unroll
    for (int k = 0; k < 32; ++k)
      a = fmaf((float)h2buf[k], Wd[k * 4 + tid], a);
    out[(size_t)row * 4 + tid] = fast_sigmoid(a);
  }
}

extern "C" void kernel_launch(void* const* d_in, const int* in_sizes, int n_in,
                              void* d_out, int out_size, void* d_ws, size_t ws_size,
                              hipStream_t stream) {
  const int*   tokens = (const int*)d_in[0];
  const float* emb    = (const float*)d_in[1];
  const float* W1     = (const float*)d_in[2];
  const float* U1     = (const float*)d_in[3];
  const float* b1     = (const float*)d_in[4];
  const float* W2     = (const float*)d_in[5];
  const float* U2     = (const float*)d_in[6];
  const float* b2     = (const float*)d_in[7];
  const float* Wd     = (const float*)d_in[8];
  const float* bd     = (const float*)d_in[9];
  float* out    = (float*)d_out;
  float* emb_zi = (float*)d_ws;         // 5000*256*4 = 5.12 MB scratch

  emb_gemm<<<dim3(VOCAB / 8), dim3(256), 0, stream>>>(emb, W1, b1, emb_zi);
  lstm_pipe<<<dim3(NB), dim3(128), 0, stream>>>(
      tokens, emb_zi, U1, W2, U2, b2, Wd, bd, out);
}